// Round 1
// baseline (76.860 us; speedup 1.0000x reference)
//
#include <hip/hip_runtime.h>

#define NROWS 8192
#define DIM   512
#define EPS   1e-8f

// One wave (64 lanes) per row. 512 floats/row = 2 float4 per lane per input.
// 4 waves per 256-thread block -> 2048 blocks, one partial sum per block.
__global__ __launch_bounds__(256) void byol_row_cos(const float* __restrict__ x,
                                                    const float* __restrict__ t,
                                                    float* __restrict__ partial) {
    const int wave = threadIdx.x >> 6;   // 0..3
    const int lane = threadIdx.x & 63;
    const int row  = blockIdx.x * 4 + wave;

    const float4* __restrict__ xr = (const float4*)(x + (size_t)row * DIM);
    const float4* __restrict__ tr = (const float4*)(t + (size_t)row * DIM);

    float dot = 0.f, nx = 0.f, nt = 0.f;
#pragma unroll
    for (int j = 0; j < 2; ++j) {
        float4 a = xr[j * 64 + lane];
        float4 b = tr[j * 64 + lane];
        dot += a.x * b.x + a.y * b.y + a.z * b.z + a.w * b.w;
        nx  += a.x * a.x + a.y * a.y + a.z * a.z + a.w * a.w;
        nt  += b.x * b.x + b.y * b.y + b.z * b.z + b.w * b.w;
    }

    // 64-lane butterfly reduction
#pragma unroll
    for (int off = 32; off > 0; off >>= 1) {
        dot += __shfl_xor(dot, off, 64);
        nx  += __shfl_xor(nx,  off, 64);
        nt  += __shfl_xor(nt,  off, 64);
    }

    __shared__ float s[4];
    if (lane == 0) {
        float denom = fmaxf(sqrtf(nx), EPS) * fmaxf(sqrtf(nt), EPS);
        s[wave] = dot / denom;
    }
    __syncthreads();
    if (threadIdx.x == 0) partial[blockIdx.x] = s[0] + s[1] + s[2] + s[3];
}

__global__ __launch_bounds__(256) void byol_finalize(const float* __restrict__ partial,
                                                     float* __restrict__ out,
                                                     int nparts) {
    float sum = 0.f;
    for (int i = threadIdx.x; i < nparts; i += 256) sum += partial[i];
#pragma unroll
    for (int off = 32; off > 0; off >>= 1) sum += __shfl_xor(sum, off, 64);

    __shared__ float s[4];
    if ((threadIdx.x & 63) == 0) s[threadIdx.x >> 6] = sum;
    __syncthreads();
    if (threadIdx.x == 0)
        out[0] = 2.0f - 2.0f * ((s[0] + s[1] + s[2] + s[3]) / (float)NROWS);
}

extern "C" void kernel_launch(void* const* d_in, const int* in_sizes, int n_in,
                              void* d_out, int out_size, void* d_ws, size_t ws_size,
                              hipStream_t stream) {
    const float* x = (const float*)d_in[0];
    const float* t = (const float*)d_in[1];
    float* out     = (float*)d_out;
    float* partial = (float*)d_ws;   // 2048 floats = 8 KB, well within ws_size

    const int nblocks = NROWS / 4;   // 2048
    byol_row_cos<<<nblocks, 256, 0, stream>>>(x, t, partial);
    byol_finalize<<<1, 256, 0, stream>>>(partial, out, nblocks);
}